// Round 1
// baseline (810.485 us; speedup 1.0000x reference)
//
#include <hip/hip_runtime.h>
#include <float.h>
#include <math.h>

#define C   1024
#define NQ  10
#define TS  256   // rows per K1 tile
#define CK  32    // cols per K1 chunk
#define G4  512   // K4 grid

// ---------------- K0: qd[k] = Qn[k] - Qn[NQ]  (normalize 11 query rows) ----
__global__ __launch_bounds__(256) void k0_qdiff(const float* __restrict__ Q,
                                                float* __restrict__ qd) {
  __shared__ float red[256];
  __shared__ float inorm[NQ + 1];
  int t = threadIdx.x;
  for (int k = 0; k <= NQ; ++k) {
    float s = 0.f;
    for (int c = t; c < C; c += 256) { float v = Q[k * C + c]; s = fmaf(v, v, s); }
    red[t] = s; __syncthreads();
    for (int st = 128; st > 0; st >>= 1) {
      if (t < st) red[t] += red[t + st];
      __syncthreads();
    }
    if (t == 0) inorm[k] = 1.0f / fmaxf(sqrtf(red[0]), 1e-12f);
    __syncthreads();
  }
  for (int k = 0; k < NQ; ++k)
    for (int c = t; c < C; c += 256)
      qd[k * C + c] = Q[k * C + c] * inorm[k] - Q[NQ * C + c] * inorm[NQ];
}

// ---------------- K1: logits L[k][n] = 100 * (qd_k . x_n) / ||x_n||  -------
// thread-per-row via LDS-transposed chunks; per-tile max -> maxp[tile][k]
__global__ __launch_bounds__(256) void k1_logits(const float* __restrict__ X,
                                                 const float* __restrict__ qd,
                                                 float* __restrict__ Lg,
                                                 float* __restrict__ maxp, int N) {
  __shared__ float sqd[NQ * C];        // 40 KB
  __shared__ float xs[CK][TS + 1];     // 32 x 257 f32 = 32.9 KB, 2-way banks only
  int t = threadIdx.x;
  int tile0 = blockIdx.x * TS;

  for (int i = t; i < NQ * C; i += 256) sqd[i] = qd[i];

  float dot[NQ];
#pragma unroll
  for (int k = 0; k < NQ; ++k) dot[k] = 0.f;
  float ss = 0.f;

  const int rl = t >> 3;          // 0..31 staging row within group
  const int c4 = (t & 7) << 2;    // 0..28 staging col
  const int NCH = C / CK;         // 32 chunks

  float4 v[8];
#pragma unroll
  for (int i = 0; i < 8; ++i) {
    int gr = tile0 + rl + i * 32;
    v[i] = (gr < N) ? *(const float4*)&X[(size_t)gr * C + c4]
                    : make_float4(0.f, 0.f, 0.f, 0.f);
  }

  for (int cc = 0; cc < NCH; ++cc) {
    __syncthreads();               // previous chunk's xs reads done
#pragma unroll
    for (int i = 0; i < 8; ++i) {
      int r = rl + i * 32;
      xs[c4 + 0][r] = v[i].x; xs[c4 + 1][r] = v[i].y;
      xs[c4 + 2][r] = v[i].z; xs[c4 + 3][r] = v[i].w;
    }
    __syncthreads();
    if (cc + 1 < NCH) {            // prefetch next chunk while computing this one
#pragma unroll
      for (int i = 0; i < 8; ++i) {
        int gr = tile0 + rl + i * 32;
        v[i] = (gr < N) ? *(const float4*)&X[(size_t)gr * C + (cc + 1) * CK + c4]
                        : make_float4(0.f, 0.f, 0.f, 0.f);
      }
    }
    const float* qp = &sqd[cc * CK];
#pragma unroll
    for (int c = 0; c < CK; c += 4) {
      float x0 = xs[c + 0][t], x1 = xs[c + 1][t];
      float x2 = xs[c + 2][t], x3 = xs[c + 3][t];
      ss = fmaf(x0, x0, fmaf(x1, x1, fmaf(x2, x2, fmaf(x3, x3, ss))));
#pragma unroll
      for (int k = 0; k < NQ; ++k) {
        const float4 q4 = *(const float4*)&qp[k * C + c];
        dot[k] = fmaf(x0, q4.x, fmaf(x1, q4.y, fmaf(x2, q4.z, fmaf(x3, q4.w, dot[k]))));
      }
    }
  }

  int myrow = tile0 + t;
  bool active = myrow < N;
  float rn = 1.0f / fmaxf(sqrtf(ss), 1e-12f);
  float lg[NQ];
#pragma unroll
  for (int k = 0; k < NQ; ++k) {
    lg[k] = active ? (100.0f * dot[k] * rn) : -FLT_MAX;
    if (active) Lg[(size_t)k * N + myrow] = lg[k];
  }

  float* red = &xs[0][0];          // reuse as 256-float scratch
  __syncthreads();
  for (int k = 0; k < NQ; ++k) {
    red[t] = lg[k]; __syncthreads();
    for (int st = 128; st > 0; st >>= 1) {
      if (t < st) red[t] = fmaxf(red[t], red[t + st]);
      __syncthreads();
    }
    if (t == 0) maxp[blockIdx.x * NQ + k] = red[0];
    __syncthreads();
  }
}

// ---------------- K2: global max per query ---------------------------------
__global__ __launch_bounds__(256) void k2_gmax(const float* __restrict__ maxp,
                                               float* __restrict__ M, int TILES) {
  __shared__ float red[256];
  int t = threadIdx.x;
  for (int k = 0; k < NQ; ++k) {
    float mm = -FLT_MAX;
    for (int i = t; i < TILES; i += 256) mm = fmaxf(mm, maxp[i * NQ + k]);
    red[t] = mm; __syncthreads();
    for (int st = 128; st > 0; st >>= 1) {
      if (t < st) red[t] = fmaxf(red[t], red[t + st]);
      __syncthreads();
    }
    if (t == 0) M[k] = red[0];
    __syncthreads();
  }
}

// ---------------- K4: per-block partial weighted sums + partial denoms -----
__global__ __launch_bounds__(256) void k4_partial(const float* __restrict__ X,
                                                  const float* __restrict__ Lg,
                                                  const float* __restrict__ M,
                                                  float* __restrict__ partial,
                                                  float* __restrict__ dsum,
                                                  int N, int rpb) {
  int g = blockIdx.x, t = threadIdx.x;
  int n0 = g * rpb;
  int n1 = min(n0 + rpb, N);
  float m[NQ];
#pragma unroll
  for (int k = 0; k < NQ; ++k) m[k] = M[k];
  float a[NQ][4];
#pragma unroll
  for (int k = 0; k < NQ; ++k) { a[k][0] = 0.f; a[k][1] = 0.f; a[k][2] = 0.f; a[k][3] = 0.f; }
  float ds[NQ];
#pragma unroll
  for (int k = 0; k < NQ; ++k) ds[k] = 0.f;

#pragma unroll 2
  for (int n = n0; n < n1; ++n) {
    float4 x4 = *(const float4*)&X[(size_t)n * C + (t << 2)];
    float w[NQ];
#pragma unroll
    for (int k = 0; k < NQ; ++k) w[k] = __expf(Lg[(size_t)k * N + n] - m[k]);
#pragma unroll
    for (int k = 0; k < NQ; ++k) {
      ds[k] += w[k];
      a[k][0] = fmaf(w[k], x4.x, a[k][0]);
      a[k][1] = fmaf(w[k], x4.y, a[k][1]);
      a[k][2] = fmaf(w[k], x4.z, a[k][2]);
      a[k][3] = fmaf(w[k], x4.w, a[k][3]);
    }
  }
#pragma unroll
  for (int k = 0; k < NQ; ++k) {
    float4 o; o.x = a[k][0]; o.y = a[k][1]; o.z = a[k][2]; o.w = a[k][3];
    *(float4*)&partial[(((size_t)(g * NQ + k)) << 10) + (t << 2)] = o;
  }
  if (t == 0) {
#pragma unroll
    for (int k = 0; k < NQ; ++k) dsum[g * NQ + k] = ds[k];
  }
}

// ---------------- K5a: pooled[c] = sum_k sum_g partial/(10*D_k) ------------
__global__ __launch_bounds__(256) void k5a_pooled(const float* __restrict__ partial,
                                                  const float* __restrict__ dsum,
                                                  float* __restrict__ pooled) {
  __shared__ float invD[NQ];
  __shared__ float r4[256][4];
  int t = threadIdx.x;
  if (t < NQ) {
    float s = 0.f;
    for (int g = 0; g < G4; ++g) s += dsum[g * NQ + t];
    invD[t] = 1.0f / (s * (float)NQ);
  }
  __syncthreads();
  int c0 = blockIdx.x * 4;
  float a0 = 0.f, a1 = 0.f, a2 = 0.f, a3 = 0.f;
  for (int idx = t; idx < G4 * NQ; idx += 256) {
    int k = idx % NQ;
    const float4 p = *(const float4*)&partial[(((size_t)idx) << 10) + c0];
    float s = invD[k];
    a0 = fmaf(p.x, s, a0); a1 = fmaf(p.y, s, a1);
    a2 = fmaf(p.z, s, a2); a3 = fmaf(p.w, s, a3);
  }
  r4[t][0] = a0; r4[t][1] = a1; r4[t][2] = a2; r4[t][3] = a3;
  __syncthreads();
  for (int st = 128; st > 0; st >>= 1) {
    if (t < st) {
      r4[t][0] += r4[t + st][0]; r4[t][1] += r4[t + st][1];
      r4[t][2] += r4[t + st][2]; r4[t][3] += r4[t + st][3];
    }
    __syncthreads();
  }
  if (t < 4) pooled[c0 + t] = r4[0][t];
}

// ---------------- K5b: out[j] = b[j] + sum_c pooled[c] * W[j][c] -----------
__global__ __launch_bounds__(256) void k5b_out(const float* __restrict__ W,
                                               const float* __restrict__ bias,
                                               const float* __restrict__ pooled,
                                               float* __restrict__ out) {
  __shared__ float sp[C];
  int t = threadIdx.x;
  for (int i = t; i < C; i += 256) sp[i] = pooled[i];
  __syncthreads();
  int wv = t >> 6, lane = t & 63;
#pragma unroll
  for (int jj = 0; jj < 8; ++jj) {
    int j = blockIdx.x * 32 + wv * 8 + jj;
    float s = 0.f;
#pragma unroll
    for (int seg = 0; seg < 4; ++seg) {
      int cbase = seg * 256 + lane * 4;
      float4 w4 = *(const float4*)&W[(size_t)j * C + cbase];
      float4 p4 = *(const float4*)&sp[cbase];
      s += w4.x * p4.x + w4.y * p4.y + w4.z * p4.z + w4.w * p4.w;
    }
#pragma unroll
    for (int off = 32; off > 0; off >>= 1) s += __shfl_down(s, off);
    if (lane == 0) out[j] = s + bias[j];
  }
}

// ---------------------------------------------------------------------------
extern "C" void kernel_launch(void* const* d_in, const int* in_sizes, int n_in,
                              void* d_out, int out_size, void* d_ws, size_t ws_size,
                              hipStream_t stream) {
  const float* X = (const float*)d_in[0];
  const float* Q = (const float*)d_in[1];
  const float* W = (const float*)d_in[2];
  const float* b = (const float*)d_in[3];
  float* out = (float*)d_out;

  int N = in_sizes[0] / C;                 // 100000
  int TILES = (N + TS - 1) / TS;           // 391
  int rpb = (N + G4 - 1) / G4;             // 196

  float* ws      = (float*)d_ws;
  float* qd      = ws;                               // NQ*C
  float* M       = qd + NQ * C;                      // 16 (padded)
  float* maxp    = M + 16;                           // TILES*NQ
  float* dsum    = maxp + ((TILES * NQ + 15) & ~15); // G4*NQ
  float* pooled  = dsum + G4 * NQ;                   // C
  float* Lg      = pooled + C;                       // NQ*N
  float* partial = Lg + (size_t)NQ * N;              // G4*NQ*C  (~20 MB)

  hipLaunchKernelGGL(k0_qdiff,  dim3(1),      dim3(256), 0, stream, Q, qd);
  hipLaunchKernelGGL(k1_logits, dim3(TILES),  dim3(256), 0, stream, X, qd, Lg, maxp, N);
  hipLaunchKernelGGL(k2_gmax,   dim3(1),      dim3(256), 0, stream, maxp, M, TILES);
  hipLaunchKernelGGL(k4_partial,dim3(G4),     dim3(256), 0, stream, X, Lg, M, partial, dsum, N, rpb);
  hipLaunchKernelGGL(k5a_pooled,dim3(C / 4),  dim3(256), 0, stream, partial, dsum, pooled);
  hipLaunchKernelGGL(k5b_out,   dim3(C / 32), dim3(256), 0, stream, W, b, pooled, out);
}